// Round 7
// baseline (166.140 us; speedup 1.0000x reference)
//
#include <hip/hip_runtime.h>

#define EPSF 1e-6f
#define POISON 0xAAAAAAAAu
#define INFB 0x7F800000u

__device__ __forceinline__ float wave_sum(float v) {
#pragma unroll
    for (int off = 32; off; off >>= 1) v += __shfl_down(v, off, 64);
    return v;
}

// 1024 blocks x 512 threads, 4 blocks/CU -> 32 waves/CU (full occupancy).
// Block b = (row = b>>1, GT-half h = b&1): all 512 row pixels vs 256 GT pts.
// Thread (g = t>>6 wave id, s = t&63): pixels x = s+{0,64,...,448} (8 px),
// wave g owns GT sub-chunk [256h+32g, +32). Mirrored 64-entry LDS chunks kill
// index wrap; per iter 1 ds_read_b64 + 1 ds_min over 8 pairs; wave ds_min
// addrs = 32 consecutive dwords (2 lanes/addr, 2-way = free).
// Cross-half merges via poison-identity global arrays:
//  - g_rm[row][512] row-min d^2 bits, atomicMin; per-row counter cnt_row:
//    SECOND finisher of a row computes term1 partials for that row.
//  - g_cm[16 slots][512] column mins; global cnt: LAST of 1024 blocks folds
//    slots, computes term2 and writes out.
// Poison contract (0xAA): 0xAAAAAAAA > any positive-float bits (uint-min
// identity); sums poison -3.03e-13f absorbed by fp32 +=; counters accept
// POISON-based and 0-based values.
__launch_bounds__(512, 8)
__global__ void chamfer_fused(const float* __restrict__ prob,
                              const float* __restrict__ gt,
                              float* __restrict__ out,
                              float* __restrict__ sums,        // [0]=sum p, [1]=sum p*d
                              unsigned int* __restrict__ cnt,
                              unsigned int* __restrict__ cnt_row,
                              unsigned int* __restrict__ g_cm,
                              unsigned int* __restrict__ g_rm)
{
    __shared__ float2 dg_s[512];         // 8 chunks x 64 (mirrored) {dy^2, gx}
    __shared__ unsigned int cm_s[512];   // mirrored column-min bits
    __shared__ unsigned int rm_s[512];   // per-pixel row-min d^2 bits
    __shared__ float p_s[512];
    __shared__ float red[16];
    __shared__ int flag_s;

    const int t = threadIdx.x;
    const int b = blockIdx.x;
    const int row = b >> 1;
    const int h = b & 1;
    const int g = t >> 6;
    const int s = t & 63;
    const int u = s & 31;
    const float maxd = __builtin_sqrtf(524288.0f);   // sqrt(512^2+512^2)
    const float eod = EPSF / maxd;

    // ---- stage GT half (chunk-mirrored: dg_s[64g+u'] = GT[256h+32g+(u'&31)])
    {
        float2 gv = ((const float2*)gt)[(h << 8) + (g << 5) + u];
        float dy = (float)row - gv.x;
        dg_s[t] = make_float2(dy * dy, gv.y);
    }
    cm_s[t] = INFB;
    rm_s[t] = INFB;
    p_s[t] = prob[(row << 9) + t];
    __syncthreads();

    // ---- per-pixel constants for the 8 owned pixels x = s + 64k
    float inv[8], ei[8], rm[8];
#pragma unroll
    for (int k = 0; k < 8; ++k) {
        float p = p_s[s + (k << 6)];
        float q = p * p;
        float iv = 1.0f / (q * q + eod);
        inv[k] = iv;
        ei[k] = EPSF * iv;
        rm[k] = 3e38f;
    }
    const float sf = (float)s;

    // ---- main loop: 32 GT points, 8 pixels each
    int j = (g << 6) + u;
#pragma unroll 4
    for (int i = 0; i < 32; ++i, ++j) {
        float2 gc = dg_s[j];                         // mirror: j+31 in chunk
        float dx0 = sf - gc.y;
        float vm;
#pragma unroll
        for (int k = 0; k < 8; ++k) {
            float dx = dx0 + (float)(k << 6);
            float d2 = fmaf(dx, dx, gc.x);
            rm[k] = fminf(rm[k], d2);
            float d = __builtin_amdgcn_sqrtf(d2);
            float vv = fmaf(d, inv[k], ei[k]);       // (d+eps)*inv
            vm = k ? fminf(vm, vv) : vv;
        }
        atomicMin(&cm_s[j], __float_as_uint(vm));
    }

    // ---- row-min merge across the 8 waves (positive floats: bit-ordered)
#pragma unroll
    for (int k = 0; k < 8; ++k)
        atomicMin(&rm_s[s + (k << 6)], __float_as_uint(rm[k]));
    __syncthreads();

    // ---- column fold (mirror halves) + global scatter into 16 slots
    if (t < 256) {
        int gg = t >> 5, uu = t & 31;
        unsigned int a = min(cm_s[(gg << 6) + uu], cm_s[(gg << 6) + 32 + uu]);
        atomicMin(&g_cm[((b & 15) << 9) + (h << 8) + t], a);
    }
    // ---- block-partial row-min -> global (cross-half merge)
    atomicMin(&g_rm[(row << 9) + t], rm_s[t]);

    // ---- per-row counter: SECOND finisher computes term1 for this row
    if (t == 0) {
        __threadfence();
        unsigned int old = atomicAdd(&cnt_row[row], 1u);
        flag_s = (old == POISON + 1u) || (old == 1u);
    }
    __syncthreads();
    if (flag_s) {
        __threadfence();
        unsigned int rb = __hip_atomic_load(&g_rm[(row << 9) + t], __ATOMIC_RELAXED, __HIP_MEMORY_SCOPE_AGENT);
        float dmin = __builtin_amdgcn_sqrtf(__uint_as_float(rb));
        float pv = wave_sum(p_s[t] * dmin);
        float sp = wave_sum(p_s[t]);
        if ((t & 63) == 0) { red[t >> 6] = pv; red[8 + (t >> 6)] = sp; }
        __syncthreads();
        if (t == 0) {
            float a = 0.f, bb = 0.f;
#pragma unroll
            for (int i = 0; i < 8; ++i) { a += red[i]; bb += red[8 + i]; }
            atomicAdd(&sums[1], a);
            atomicAdd(&sums[0], bb);
        }
    }
    __syncthreads();   // protect flag_s reuse (uniform: all threads reach)

    // ---- global counter: LAST of 1024 blocks finalizes term2 + output
    if (t == 0) {
        __threadfence();
        unsigned int old = atomicAdd(cnt, 1u);
        flag_s = (old == POISON + 1023u) || (old == 1023u);
    }
    __syncthreads();
    if (!flag_s) return;

    __threadfence();
    unsigned int mv = __hip_atomic_load(&g_cm[t], __ATOMIC_RELAXED, __HIP_MEMORY_SCOPE_AGENT);
#pragma unroll
    for (int sl = 1; sl < 16; ++sl) {
        unsigned int w = __hip_atomic_load(&g_cm[(sl << 9) + t], __ATOMIC_RELAXED, __HIP_MEMORY_SCOPE_AGENT);
        mv = (w < mv) ? w : mv;
    }
    float v = fminf(fmaxf(__uint_as_float(mv), 0.0f), maxd);
    float s2 = wave_sum(v);
    if ((t & 63) == 0) red[t >> 6] = s2;
    __syncthreads();
    if (t == 0) {
        float tsum = 0.f;
#pragma unroll
        for (int i = 0; i < 8; ++i) tsum += red[i];
        float term2 = tsum * (1.0f / 512.0f);
        float sA = __hip_atomic_load(&sums[0], __ATOMIC_RELAXED, __HIP_MEMORY_SCOPE_AGENT);
        float sB = __hip_atomic_load(&sums[1], __ATOMIC_RELAXED, __HIP_MEMORY_SCOPE_AGENT);
        out[0] = sB / (sA + EPSF) + term2;
    }
}

extern "C" void kernel_launch(void* const* d_in, const int* in_sizes, int n_in,
                              void* d_out, int out_size, void* d_ws, size_t ws_size,
                              hipStream_t stream) {
    const float* prob = (const float*)d_in[0];   // [512*512]
    const float* gt   = (const float*)d_in[1];   // [512,2]
    // d_in[2] (all_img_locations) implicit from pixel index; unused.
    float* out = (float*)d_out;

    float* sums            = (float*)d_ws;                          // 8 B
    unsigned int* cnt      = (unsigned int*)((char*)d_ws + 8);      // 4 B
    unsigned int* cnt_row  = (unsigned int*)((char*)d_ws + 256);    // 2 KB
    unsigned int* g_cm     = (unsigned int*)((char*)d_ws + 4096);   // 32 KB
    unsigned int* g_rm     = (unsigned int*)((char*)d_ws + 65536);  // 1 MB

    chamfer_fused<<<1024, 512, 0, stream>>>(prob, gt, out, sums, cnt, cnt_row, g_cm, g_rm);
}

// Round 8
// 105.049 us; speedup vs baseline: 1.5815x; 1.5815x over previous
//
#include <hip/hip_runtime.h>

#define EPSF 1e-6f
#define POISON 0xAAAAAAAAu
#define INFB 0x7F800000u

__device__ __forceinline__ float wave_sum(float v) {
#pragma unroll
    for (int off = 32; off; off >>= 1) v += __shfl_down(v, off, 64);
    return v;
}

// 1024 blocks x 512 threads, launch_bounds(512,8) -> 4 blocks/CU = 32 waves/CU.
// Block b = (row = b>>1, pixel-half h = b&1): 256 pixels vs ALL 512 GT points.
// PIXEL split (not GT split, R7's mistake): each pixel lives in exactly one
// block, so term1 (row-min) is fully in-block -- zero new global traffic vs R5.
// Thread (g = t>>6, s = t&63): wave g owns GT chunk g (64 pts, mirrored LDS,
// wave-uniform base -> ds_min on 64 consecutive dwords, 2-way = free); lane
// owns 4 pixels x = 256h + s + {0,64,128,192}. Per iter: 1 ds_read_b64 +
// 1 ds_min amortized over 4 pairs.
// Poison contract (0xAA): g_cm 0xAAAAAAAA uint-min identity (> any positive
// float bits); sums poison -3.03e-13f absorbed by fp32 +=; cnt accepts
// POISON+1023 (and 1023 fallback).
__launch_bounds__(512, 8)
__global__ void chamfer_fused(const float* __restrict__ prob,
                              const float* __restrict__ gt,
                              float* __restrict__ out,
                              float* __restrict__ sums,        // [0]=sum p, [1]=sum p*d
                              unsigned int* __restrict__ cnt,
                              unsigned int* __restrict__ g_cm) // [16 slots][512]
{
    __shared__ float2 dg_s[1024];        // 8 chunks x 128 (mirrored) {dy^2, gx}
    __shared__ unsigned int cm_s[1024];  // mirrored column-min bits
    __shared__ unsigned int rm_s[256];   // per-pixel row-min d^2 bits (this half)
    __shared__ float p_s[256];
    __shared__ float red[16];
    __shared__ int last_s;

    const int t = threadIdx.x;
    const int b = blockIdx.x;
    const int row = b >> 1;
    const int h = b & 1;
    const int g = t >> 6;
    const int s = t & 63;
    const float maxd = __builtin_sqrtf(524288.0f);   // sqrt(512^2+512^2)
    const float eod = EPSF / maxd;

    // ---- stage GT (chunk-mirrored: dg_s[c*128 + i] = GT[c*64 + (i&63)])
    {
        float2 gv = ((const float2*)gt)[t];          // t == GT index
        float dy = (float)row - gv.x;
        float2 v = make_float2(dy * dy, gv.y);
        dg_s[(g << 7) + s]      = v;
        dg_s[(g << 7) + 64 + s] = v;
    }
    cm_s[t]       = INFB;
    cm_s[t + 512] = INFB;
    if (t < 256) {
        rm_s[t] = INFB;
        p_s[t] = prob[(row << 9) + (h << 8) + t];
    }
    __syncthreads();

    // ---- per-pixel constants for the 4 owned pixels x = 256h + s + 64k
    float inv[4], ei[4], rm[4];
#pragma unroll
    for (int k = 0; k < 4; ++k) {
        float p = p_s[s + (k << 6)];
        float q = p * p;
        float iv = 1.0f / (q * q + eod);
        inv[k] = iv;
        ei[k] = EPSF * iv;
        rm[k] = 3e38f;
    }
    const float sfp = (float)((h << 8) + s);

    // ---- main loop: 64 GT points (wave-exclusive chunk), 4 pixels each
    int j = (g << 7) + s;
#pragma unroll 4
    for (int i = 0; i < 64; ++i, ++j) {
        float2 gc = dg_s[j];                         // mirror: j+63 in chunk
        float dx0 = sfp - gc.y;
        float vm;
#pragma unroll
        for (int k = 0; k < 4; ++k) {
            float dx = dx0 + (float)(k << 6);
            float d2 = fmaf(dx, dx, gc.x);
            rm[k] = fminf(rm[k], d2);
            float d = __builtin_amdgcn_sqrtf(d2);
            float vv = fmaf(d, inv[k], ei[k]);       // (d+eps)*inv
            vm = k ? fminf(vm, vv) : vv;
        }
        atomicMin(&cm_s[j], __float_as_uint(vm));    // 64 consecutive dwords/wave
    }

    // ---- row-min merge across the 8 waves (positive floats: bit-ordered)
#pragma unroll
    for (int k = 0; k < 4; ++k)
        atomicMin(&rm_s[s + (k << 6)], __float_as_uint(rm[k]));
    __syncthreads();

    // ---- column fold (mirror halves) + global scatter into 16 slots
    {
        int c = t >> 6, i2 = t & 63;
        unsigned int a = min(cm_s[(c << 7) + i2], cm_s[(c << 7) + 64 + i2]);
        atomicMin(&g_cm[((b & 15) << 9) + t], a);    // column index == t
    }

    // ---- term1 partials: fully in-block (waves 0..3 cover the 256 pixels)
    if (t < 256) {
        float dmin = __builtin_amdgcn_sqrtf(__uint_as_float(rm_s[t]));
        float pv = wave_sum(p_s[t] * dmin);
        float sp = wave_sum(p_s[t]);
        if ((t & 63) == 0) { red[t >> 6] = pv; red[8 + (t >> 6)] = sp; }
    }
    __syncthreads();
    if (t == 0) {
        float a = red[0] + red[1] + red[2] + red[3];
        float bb = red[8] + red[9] + red[10] + red[11];
        atomicAdd(&sums[1], a);
        atomicAdd(&sums[0], bb);
        __threadfence();
        unsigned int old = atomicAdd(cnt, 1u);
        last_s = (old == POISON + 1023u) || (old == 1023u);
    }
    __syncthreads();
    if (!last_s) return;

    // ---- last of 1024 blocks finalizes term2 + output
    __threadfence();
    unsigned int mv = __hip_atomic_load(&g_cm[t], __ATOMIC_RELAXED, __HIP_MEMORY_SCOPE_AGENT);
#pragma unroll
    for (int sl = 1; sl < 16; ++sl) {
        unsigned int w = __hip_atomic_load(&g_cm[(sl << 9) + t], __ATOMIC_RELAXED, __HIP_MEMORY_SCOPE_AGENT);
        mv = (w < mv) ? w : mv;
    }
    float v = fminf(fmaxf(__uint_as_float(mv), 0.0f), maxd);
    float s2 = wave_sum(v);
    if ((t & 63) == 0) red[t >> 6] = s2;
    __syncthreads();
    if (t == 0) {
        float tsum = 0.f;
#pragma unroll
        for (int i = 0; i < 8; ++i) tsum += red[i];
        float term2 = tsum * (1.0f / 512.0f);
        float sA = __hip_atomic_load(&sums[0], __ATOMIC_RELAXED, __HIP_MEMORY_SCOPE_AGENT);
        float sB = __hip_atomic_load(&sums[1], __ATOMIC_RELAXED, __HIP_MEMORY_SCOPE_AGENT);
        out[0] = sB / (sA + EPSF) + term2;
    }
}

extern "C" void kernel_launch(void* const* d_in, const int* in_sizes, int n_in,
                              void* d_out, int out_size, void* d_ws, size_t ws_size,
                              hipStream_t stream) {
    const float* prob = (const float*)d_in[0];   // [512*512]
    const float* gt   = (const float*)d_in[1];   // [512,2]
    // d_in[2] (all_img_locations) implicit from pixel index; unused.
    float* out = (float*)d_out;

    float* sums        = (float*)d_ws;                        // 8 B
    unsigned int* cnt  = (unsigned int*)((char*)d_ws + 8);    // 4 B
    unsigned int* g_cm = (unsigned int*)((char*)d_ws + 128);  // 16*512*4 = 32 KB

    chamfer_fused<<<1024, 512, 0, stream>>>(prob, gt, out, sums, cnt, g_cm);
}

// Round 9
// 97.334 us; speedup vs baseline: 1.7069x; 1.0793x over previous
//
#include <hip/hip_runtime.h>

#define EPSF 1e-6f
#define INFB 0x7F800000u

__device__ __forceinline__ float wave_sum(float v) {
#pragma unroll
    for (int off = 32; off; off >>= 1) v += __shfl_down(v, off, 64);
    return v;
}

// ---------------- Kernel A: the 134M-pair loop ----------------
// 1024 blocks x 512 threads, launch_bounds(512,8) -> 4 blocks/CU = 32 waves/CU.
// Block b = (row = b>>1, GT-half h = b&1): ALL 512 row pixels vs 256 GT points.
// Wave g owns GT chunk [256h+32g, +32) staged mirrored in dg_s[g*64 + (q&31)];
// lanes s and s+32 walk the same column j = g*64 + (s&31) + i (same-address
// ds ops: read broadcasts, 2-way atomic is free per m136). Lane owns 8 px
// x = s + {0..448}: DS per iter amortized over 8 pairs (R5's winning ratio)
// at 4 blocks/CU (R8's winning occupancy). 32-iter loop.
// Cross-block merges are PLAIN stream-ordered: row-min partials ->
// g_rm[row*512+px] atomicMin (poison 0xAAAAAAAA > any positive-float bits =
// valid uint-min identity); column mins -> g_cm 16-slot scatter. Term1/term2
// reductions happen in kernels B/C after A completes (no fences, no counters).
__launch_bounds__(512, 8)
__global__ void chamfer_pairs(const float* __restrict__ prob,
                              const float* __restrict__ gt,
                              unsigned int* __restrict__ g_cm,  // [16][512]
                              unsigned int* __restrict__ g_rm)  // [512][512]
{
    __shared__ float2 dg_s[512];         // 8 chunks x 64 (mirrored 32x2) {dy^2, gx}
    __shared__ unsigned int cm_s[512];   // mirrored column-min bits
    __shared__ unsigned int rm_s[512];   // per-pixel row-min d^2 bits

    const int t = threadIdx.x;
    const int b = blockIdx.x;
    const int row = b >> 1;
    const int h = b & 1;
    const int g = t >> 6;
    const int s = t & 63;
    const int u = s & 31;
    const float maxd = __builtin_sqrtf(524288.0f);   // sqrt(512^2+512^2)
    const float eod = EPSF / maxd;

    // ---- stage GT chunk (mirrored): dg_s[t] = GT[256h + 32g + u]
    {
        float2 gv = ((const float2*)gt)[(h << 8) + (g << 5) + u];
        float dy = (float)row - gv.x;
        dg_s[t] = make_float2(dy * dy, gv.y);
    }
    cm_s[t] = INFB;
    rm_s[t] = INFB;
    __syncthreads();

    // ---- per-pixel constants for the 8 owned pixels x = s + 64k
    float inv[8], ei[8], rm[8];
#pragma unroll
    for (int k = 0; k < 8; ++k) {
        float p = prob[(row << 9) + s + (k << 6)];   // coalesced per k
        float q = p * p;
        float iv = 1.0f / (q * q + eod);
        inv[k] = iv;
        ei[k] = EPSF * iv;
        rm[k] = 3e38f;
    }
    const float sf = (float)s;

    // ---- main loop: 32 GT points, 8 pixels each
    int j = (g << 6) + u;
#pragma unroll 4
    for (int i = 0; i < 32; ++i, ++j) {
        float2 gc = dg_s[j];                         // mirror: j+31 in chunk
        float dx0 = sf - gc.y;
        float vm;
#pragma unroll
        for (int k = 0; k < 8; ++k) {
            float dx = dx0 + (float)(k << 6);
            float d2 = fmaf(dx, dx, gc.x);
            rm[k] = fminf(rm[k], d2);
            float d = __builtin_amdgcn_sqrtf(d2);
            float vv = fmaf(d, inv[k], ei[k]);       // (d+eps)*inv
            vm = k ? fminf(vm, vv) : vv;
        }
        atomicMin(&cm_s[j], __float_as_uint(vm));
    }

    // ---- row-min merge across the 8 waves, then one global atomic per pixel
#pragma unroll
    for (int k = 0; k < 8; ++k)
        atomicMin(&rm_s[s + (k << 6)], __float_as_uint(rm[k]));
    __syncthreads();
    atomicMin(&g_rm[(row << 9) + t], rm_s[t]);

    // ---- column fold (mirror halves) + 16-slot global scatter
    if (t < 256) {
        int c = t >> 5, u2 = t & 31;
        unsigned int a = min(cm_s[(c << 6) + u2], cm_s[(c << 6) + 32 + u2]);
        atomicMin(&g_cm[((row & 15) << 9) + (h << 8) + (c << 5) + u2], a);
    }
}

// ---------------- Kernel B: term1 reduction ----------------
// 512 blocks x 512 threads; runs after A (stream order => visibility).
// sums poison -3.03e-13f is absorbed by the fp32 atomicAdd.
__global__ void chamfer_term1(const float* __restrict__ prob,
                              const unsigned int* __restrict__ g_rm,
                              float* __restrict__ sums) {
    __shared__ float red[16];
    const int t = threadIdx.x;
    const int r = blockIdx.x;
    float p = prob[(r << 9) + t];
    float dmin = __builtin_amdgcn_sqrtf(__uint_as_float(g_rm[(r << 9) + t]));
    float pv = wave_sum(p * dmin);
    float sp = wave_sum(p);
    if ((t & 63) == 0) { red[t >> 6] = pv; red[8 + (t >> 6)] = sp; }
    __syncthreads();
    if (t == 0) {
        float a = red[0] + red[1] + red[2] + red[3] + red[4] + red[5] + red[6] + red[7];
        float bb = red[8] + red[9] + red[10] + red[11] + red[12] + red[13] + red[14] + red[15];
        atomicAdd(&sums[1], a);
        atomicAdd(&sums[0], bb);
    }
}

// ---------------- Kernel C: term2 fold + combine ----------------
__global__ void chamfer_final(const float* __restrict__ sums,
                              const unsigned int* __restrict__ g_cm,
                              float* __restrict__ out) {
    __shared__ float red[8];
    const int t = threadIdx.x;   // 512 threads, 1 block
    const float maxd = __builtin_sqrtf(524288.0f);
    unsigned int mv = g_cm[t];
#pragma unroll
    for (int sl = 1; sl < 16; ++sl) {
        unsigned int w = g_cm[(sl << 9) + t];
        mv = (w < mv) ? w : mv;
    }
    float v = fminf(fmaxf(__uint_as_float(mv), 0.0f), maxd);
    float s2 = wave_sum(v);
    if ((t & 63) == 0) red[t >> 6] = s2;
    __syncthreads();
    if (t == 0) {
        float tsum = red[0] + red[1] + red[2] + red[3] + red[4] + red[5] + red[6] + red[7];
        float term2 = tsum * (1.0f / 512.0f);
        out[0] = sums[1] / (sums[0] + EPSF) + term2;
    }
}

extern "C" void kernel_launch(void* const* d_in, const int* in_sizes, int n_in,
                              void* d_out, int out_size, void* d_ws, size_t ws_size,
                              hipStream_t stream) {
    const float* prob = (const float*)d_in[0];   // [512*512]
    const float* gt   = (const float*)d_in[1];   // [512,2]
    // d_in[2] (all_img_locations) implicit from pixel index; unused.
    float* out = (float*)d_out;

    float* sums        = (float*)d_ws;                          // 8 B (poison-identity)
    unsigned int* g_cm = (unsigned int*)((char*)d_ws + 128);    // 32 KB
    unsigned int* g_rm = (unsigned int*)((char*)d_ws + 65536);  // 1 MB

    chamfer_pairs<<<1024, 512, 0, stream>>>(prob, gt, g_cm, g_rm);
    chamfer_term1<<<512, 512, 0, stream>>>(prob, g_rm, sums);
    chamfer_final<<<1, 512, 0, stream>>>(sums, g_cm, out);
}

// Round 10
// 83.371 us; speedup vs baseline: 1.9928x; 1.1675x over previous
//
#include <hip/hip_runtime.h>

#define EPSF 1e-6f
#define INFB 0x7F800000u

__device__ __forceinline__ float wave_sum(float v) {
#pragma unroll
    for (int off = 32; off; off >>= 1) v += __shfl_down(v, off, 64);
    return v;
}
__device__ __forceinline__ float wave_min_all(float v) {   // butterfly: all lanes get min
#pragma unroll
    for (int off = 32; off; off >>= 1) v = fminf(v, __shfl_xor(v, off, 64));
    return v;
}
__device__ __forceinline__ float wave_max_all(float v) {
#pragma unroll
    for (int off = 32; off; off >>= 1) v = fmaxf(v, __shfl_xor(v, off, 64));
    return v;
}

// ---------------- Kernel A: term1 brute force (NO term2 chain) ----------------
// 512 blocks (1 row) x 512 threads. Wave g owns GT chunk g (64 pts, mirrored
// LDS); lane owns 8 px x = s+64k. Per pair: v_sub + v_fma + v_min ONLY (no
// sqrt, no LDS atomic in loop). Also reduces per-row max(p) -> g_bmax[row]
// (plain store; stream order makes it visible to kernel C).
// sums poison (-3.03e-13f from 0xAA) is absorbed by the fp32 atomicAdd.
__launch_bounds__(512, 4)
__global__ void chamfer_t1(const float* __restrict__ prob,
                           const float* __restrict__ gt,
                           float* __restrict__ sums,     // [0]=sum p, [1]=sum p*dmin
                           float* __restrict__ g_bmax) { // [512] per-row max p
    __shared__ float2 dg_s[1024];        // 8 chunks x 128 (mirrored 64x2) {dy^2, gx}
    __shared__ unsigned int rm_s[512];   // per-pixel row-min d^2 bits
    __shared__ float red[24];

    const int t = threadIdx.x;
    const int row = blockIdx.x;
    const int g = t >> 6;
    const int s = t & 63;

    {
        float2 gv = ((const float2*)gt)[t];          // (gy, gx); t == GT index
        float dy = (float)row - gv.x;
        float2 v = make_float2(dy * dy, gv.y);
        dg_s[(g << 7) + s]      = v;
        dg_s[(g << 7) + 64 + s] = v;
    }
    rm_s[t] = INFB;
    __syncthreads();

    float rm[8], sfk[8];
#pragma unroll
    for (int k = 0; k < 8; ++k) { rm[k] = 3e38f; sfk[k] = (float)(s + (k << 6)); }

    int j = (g << 7) + s;
#pragma unroll 4
    for (int i = 0; i < 64; ++i, ++j) {
        float2 gc = dg_s[j];                         // mirror: j+63 stays in chunk
#pragma unroll
        for (int k = 0; k < 8; ++k) {
            float dx = sfk[k] - gc.y;                // exact (24-bit fit)
            float d2 = fmaf(dx, dx, gc.x);
            rm[k] = fminf(rm[k], d2);
        }
    }

#pragma unroll
    for (int k = 0; k < 8; ++k)                      // positive floats: bit-ordered
        atomicMin(&rm_s[s + (k << 6)], __float_as_uint(rm[k]));
    __syncthreads();

    float p = prob[(row << 9) + t];
    float dmin = __builtin_amdgcn_sqrtf(__uint_as_float(rm_s[t]));
    float pv = wave_sum(p * dmin);
    float sp = wave_sum(p);
    float pm = wave_max_all(p);
    if ((t & 63) == 0) { red[t >> 6] = pv; red[8 + (t >> 6)] = sp; red[16 + (t >> 6)] = pm; }
    __syncthreads();
    if (t == 0) {
        float a = 0.f, b = 0.f, m = 0.f;
#pragma unroll
        for (int i = 0; i < 8; ++i) {
            a += red[i]; b += red[8 + i]; m = fmaxf(m, red[16 + i]);
        }
        atomicAdd(&sums[1], a);
        atomicAdd(&sums[0], b);
        g_bmax[row] = m;
    }
}

// ---------------- Kernel C: term2 exact ring search ----------------
// 512 blocks x 64 threads: one wave per GT column. Expanding Chebyshev rings
// from the rounded GT cell; EXACT stop rule: any unscanned pixel in ring >= r
// has d >= r-1.5 (|round-gt| <= 1, +0.5 slack), so its value
// (d+eps)/(p4+eod) >= (r-1.5+eps)/denom_lb where denom_lb = maxp^4+eod >=
// every denominator. Break when that bound >= min(best, maxd) (maxd because
// the result is clipped there). Guaranteed break by r~727. Value math mirrors
// the reference bit-for-bit: mul/mul/add d2, IEEE sqrt, (p*p)*(p*p), true div.
__launch_bounds__(64, 8)
__global__ void chamfer_t2(const float* __restrict__ prob,
                           const float* __restrict__ gt,
                           const float* __restrict__ g_bmax,
                           float* __restrict__ g_t2) {  // [512] per-column result
    const int m = blockIdx.x;
    const int lane = threadIdx.x;
    const float maxd = __builtin_sqrtf(524288.0f);   // 724.0773
    const float eod = EPSF / maxd;

    // global max(p) from the 512 per-row maxes
    float mp = 0.f;
#pragma unroll
    for (int i = 0; i < 8; ++i) mp = fmaxf(mp, g_bmax[lane + (i << 6)]);
    mp = wave_max_all(mp);
    float mq = mp * mp;
    const float denom_lb = mq * mq + eod;            // upper bound of every denom

    float2 gv = ((const float2*)gt)[m];              // (gy, gx)
    const float gy = gv.x, gx = gv.y;
    int cy = (int)(gy + 0.5f); cy = cy > 511 ? 511 : cy;
    int cx = (int)(gx + 0.5f); cx = cx > 511 ? 511 : cx;

    float best = __builtin_inff();
    for (int r = 0; r <= 750; ++r) {
        float dlb = fmaxf((float)r - 1.5f, 0.0f);
        float bnd = (dlb + EPSF) / denom_lb;
        if (bnd >= fminf(best, maxd)) break;

        int cells = r ? 8 * r : 1;
        float lval = __builtin_inff();
        for (int base = 0; base < cells; base += 64) {
            int c = base + lane;
            if (c < cells) {
                int dy, dx;
                if (r == 0) { dy = 0; dx = 0; }
                else {
                    int side = 2 * r + 1;
                    if (c < side)            { dy = -r; dx = c - r; }
                    else if (c < 2 * side)   { dy =  r; dx = (c - side) - r; }
                    else {
                        int c2 = c - 2 * side;            // 0 .. 4r-3
                        if (c2 < 2 * r - 1)  { dx = -r; dy = c2 - (r - 1); }
                        else                 { dx =  r; dy = (c2 - (2 * r - 1)) - (r - 1); }
                    }
                }
                int py = cy + dy, px = cx + dx;
                if (py >= 0 && py < 512 && px >= 0 && px < 512) {
                    float p = prob[(py << 9) + px];
                    float fy = (float)py - gy;
                    float fx = (float)px - gx;
                    float d2 = fy * fy + fx * fx;     // ref: mul+mul+add (no fma)
                    float d  = __builtin_sqrtf(d2);   // IEEE sqrt
                    float pq = p * p;
                    float p4 = pq * pq;               // ref: (p^2)^2
                    float v  = (d + EPSF) / (p4 + eod);
                    lval = fminf(lval, v);
                }
            }
        }
        lval = wave_min_all(lval);
        best = fminf(best, lval);
    }
    if (lane == 0) g_t2[m] = fminf(fmaxf(best, 0.0f), maxd);
}

// ---------------- Kernel D: combine ----------------
__global__ void chamfer_final(const float* __restrict__ sums,
                              const float* __restrict__ g_t2,
                              float* __restrict__ out) {
    __shared__ float red[8];
    const int t = threadIdx.x;                       // 1 block x 512
    float s2 = wave_sum(g_t2[t]);
    if ((t & 63) == 0) red[t >> 6] = s2;
    __syncthreads();
    if (t == 0) {
        float tot = red[0] + red[1] + red[2] + red[3] + red[4] + red[5] + red[6] + red[7];
        out[0] = sums[1] / (sums[0] + EPSF) + tot * (1.0f / 512.0f);
    }
}

extern "C" void kernel_launch(void* const* d_in, const int* in_sizes, int n_in,
                              void* d_out, int out_size, void* d_ws, size_t ws_size,
                              hipStream_t stream) {
    const float* prob = (const float*)d_in[0];   // [512*512]
    const float* gt   = (const float*)d_in[1];   // [512,2]
    // d_in[2] (all_img_locations) implicit from pixel index; unused.
    float* out = (float*)d_out;

    float* sums   = (float*)d_ws;                     // 8 B (poison-absorbing)
    float* g_bmax = (float*)((char*)d_ws + 256);      // 2 KB, fully overwritten by A
    float* g_t2   = (float*)((char*)d_ws + 4096);     // 2 KB, fully overwritten by C

    chamfer_t1<<<512, 512, 0, stream>>>(prob, gt, sums, g_bmax);
    chamfer_t2<<<512, 64, 0, stream>>>(prob, gt, g_bmax, g_t2);
    chamfer_final<<<1, 512, 0, stream>>>(sums, g_t2, out);
}